// Round 13
// baseline (163.415 us; speedup 1.0000x reference)
//
#include <hip/hip_runtime.h>
#include <hip/hip_bf16.h>

#define NN 126   // nodes
#define TT 24    // seq len
#define FF 17    // input feat
#define HH 100   // hidden
#define NMT 25   // M tiles (400 gate-interleaved rows)

// ---------- MFMA fragment geometry (identical to R10/R11) ----------
//  L0, kt 0..3  (K=128): k<17 Wih0 | k==17 bias0 | k=18+j Whh0 (j<100) | pad 118..127
//  L1, kt 0..6  (K=224): k==0 bias1(ones col) | pad 1..3 | k=4+j Wih1 | k=104+j Whh1 | pad 204..223
// LDS (shorts): Al[4][25][64][8]=51200 | B24l[7][64][8]=3584 (L1 A, tile 24)
//             | X0[2buf][4kt][2nh][64][8]=8192 | X1[2buf][7kt][2nh][64][8]=14336
#define AL_SH   51200
#define B24_SH  (AL_SH)
#define X0_SH   (AL_SH + 3584)
#define X1_SH   (X0_SH + 8192)
#define X0BUF 4096
#define X1BUF 7168
#define TOT_SH  (X1_SH + 2 * X1BUF)        // 77312 shorts
#define LDS_BYTES (TOT_SH * 2)             // 154,624 B (<160 KiB)
#define NTH 768                            // 12 waves, 3 waves/SIMD

typedef __attribute__((ext_vector_type(8))) short short8v;
typedef __attribute__((ext_vector_type(4))) float float4v;

__device__ __forceinline__ short f2bf(float f) {
    union { float f; unsigned u; } v; v.f = f;
    unsigned r = v.u + 0x7FFFu + ((v.u >> 16) & 1u);   // RNE
    return (short)(r >> 16);
}
#define LOG2E 1.4426950408889634f
__device__ __forceinline__ float sigm_(float x) {
    return __builtin_amdgcn_rcpf(1.0f + __builtin_amdgcn_exp2f(-LOG2E * x));
}
__device__ __forceinline__ float tanh_(float x) {
    return 1.0f - 2.0f * __builtin_amdgcn_rcpf(1.0f + __builtin_amdgcn_exp2f((2.0f * LOG2E) * x));
}

// ---------------- fused: prep + 12-wave skewed dbuf MFMA LSTM (acc0/acc1 overlap) ----------------
__global__ __launch_bounds__(NTH, 3)
void lstm_o12(const float* __restrict__ x,
              const float* __restrict__ Wih0, const float* __restrict__ Whh0,
              const float* __restrict__ bih0, const float* __restrict__ bhh0,
              const float* __restrict__ Wih1, const float* __restrict__ Whh1,
              const float* __restrict__ bih1, const float* __restrict__ bhh1,
              const float* __restrict__ wlin, const float* __restrict__ blin,
              const float* __restrict__ wend, const float* __restrict__ bend,
              float* __restrict__ out)
{
    extern __shared__ short lds_s[];
    short* Al   = lds_s;                 // L0 weights [kt][mt][lane][e] (read-only after init)
    short* B24l = lds_s + B24_SH;        // L1 weights, tile 24 [kt 0..6][lane][e]
    short* X0   = lds_s + X0_SH;         // [buf][kt][nh][lane][e]
    short* X1   = lds_s + X1_SH;         // [buf][kt][nh][lane][e]
    float* red  = (float*)lds_s;         // overlay over Al, epilogue only

    const int n   = blockIdx.x >> 1;
    const int bh  = blockIdx.x & 1;                 // batch half (32 each)
    const int tid = threadIdx.x, lane = tid & 63, w = tid >> 6;   // 12 waves
    const int cl  = lane & 15, q = lane >> 4;
    const int mt0 = w * 2;                          // waves 0..11: tiles 2w,2w+1; w11 also tile 24 (mi=2)
    const bool w11 = (w == 11);
    const int nmt = w11 ? 3 : 2;

    // ---- init 0: zero all LDS ----
    {
        const short8v zz = {0,0,0,0,0,0,0,0};
        for (int i = tid; i < TOT_SH / 8; i += NTH)
            *(short8v*)(lds_s + (size_t)i * 8) = zz;
    }
    __syncthreads();   // zeros visible before scatter-fill

    // ---- init 1: L0 weights -> Al (fp32 coalesced read, bf16 LDS scatter) ----
    {
        const float* W = Whh0 + (size_t)n * 40000;        // [orl 0..399][j 0..99], k = 18+j
        for (int i = tid; i < 40000; i += NTH) {
            const int orl = i / 100, j = i - orl * 100;
            const int g = orl / 100, cell = orl - g * 100;
            const int gr = cell * 4 + g;
            const int k = 18 + j;
            Al[(((k >> 5) * NMT + (gr >> 4)) * 64 + ((((k >> 3) & 3) << 4) | (gr & 15))) * 8 + (k & 7)]
                = f2bf(W[i]);
        }
    }
    {
        const float* W = Wih0 + (size_t)n * 6800;         // [orl][k 0..16], kt0
        for (int i = tid; i < 6800; i += NTH) {
            const int orl = i / 17, k = i - orl * 17;
            const int g = orl / 100, cell = orl - g * 100;
            const int gr = cell * 4 + g;
            Al[((gr >> 4) * 64 + ((((k >> 3) & 3) << 4) | (gr & 15))) * 8 + (k & 7)] = f2bf(W[i]);
        }
    }
    if (tid < 400) {                                      // L0 bias at k=17 (kt0, kq2, e1)
        const int g = tid / 100, cell = tid - g * 100;
        const int gr = cell * 4 + g;
        const int orow = n * 400 + tid;
        Al[((gr >> 4) * 64 + ((2 << 4) | (gr & 15))) * 8 + 1] = f2bf(bih0[orow] + bhh0[orow]);
    }
    // ---- init 1b: L1 weights of tile 24 -> B24l (A-frag layout) ----
    for (int i = tid; i < 7 * 64; i += NTH) {
        const int kt = i >> 6, l = i & 63;
        const int row16 = l & 15, kq = l >> 4;
        const int gr = 24 * 16 + row16;                   // rows 384..399
        const int cell = gr >> 2, g = gr & 3;
        const int orow = n * 400 + g * HH + cell;
        const float* Wi = Wih1 + (size_t)orow * HH;
        const float* Wh = Whh1 + (size_t)orow * HH;
        short8v pv;
        #pragma unroll
        for (int e = 0; e < 8; ++e) {
            const int k = kt * 32 + kq * 8 + e;
            float f = 0.0f;
            if (k == 0)                      f = bih1[orow] + bhh1[orow];
            else if (k >= 4 && k < 4 + HH)   f = Wi[k - 4];
            else if (k >= 104 && k < 104+HH) f = Wh[k - 104];
            pv[e] = f2bf(f);
        }
        *(short8v*)(B24l + (size_t)i * 8) = pv;
    }

    // ---- init 2: L1 weights (tiles 2w, 2w+1) -> wr1 regs ----
    short8v wr1[2][7];
    #pragma unroll
    for (int mi = 0; mi < 2; ++mi) {
        const int gr = (mt0 + mi) * 16 + cl;
        const int cell = gr >> 2, g = gr & 3;
        const int orow = n * 400 + g * HH + cell;
        const float* Wi = Wih1 + (size_t)orow * HH;
        const float* Wh = Whh1 + (size_t)orow * HH;
        #pragma unroll
        for (int kt = 0; kt < 7; ++kt) {
            const int k0 = kt * 32 + q * 8;               // chunk base, multiple of 8
            float v[8];
            #pragma unroll
            for (int e = 0; e < 8; ++e) v[e] = 0.0f;
            if (k0 == 0) {                                // mixed: bias | pad | Wih1 j0..3
                v[0] = bih1[orow] + bhh1[orow];
                v[4] = Wi[0]; v[5] = Wi[1]; v[6] = Wi[2]; v[7] = Wi[3];
            } else if (k0 <= 96) {                        // pure Wih1, j = k0-4+e
                #pragma unroll
                for (int e = 0; e < 8; ++e) v[e] = Wi[k0 - 4 + e];
            } else if (k0 >= 104 && k0 <= 192) {          // pure Whh1, j = k0-104+e
                #pragma unroll
                for (int e = 0; e < 8; ++e) v[e] = Wh[k0 - 104 + e];
            } else if (k0 == 200) {                       // mixed: Whh1 j96..99 | pad
                v[0] = Wh[96]; v[1] = Wh[97]; v[2] = Wh[98]; v[3] = Wh[99];
            }
            short8v pv;
            #pragma unroll
            for (int e = 0; e < 8; ++e) pv[e] = f2bf(v[e]);
            wr1[mi][kt] = pv;
        }
    }

    // hoisted per-thread LDS scatter element-offsets (within a buffer)
    int aX0h1[3][2], aX1h1[3][2], aX1h2[3][2];
    #pragma unroll
    for (int mi = 0; mi < 3; ++mi) {
        const int cell = (mt0 + mi) * 4 + q;              // w11/mi=2 -> tile 24
        #pragma unroll
        for (int nh = 0; nh < 2; ++nh) {
            { const int k = 18 + cell;
              aX0h1[mi][nh] = (((k >> 5) * 2 + nh) * 64 + ((((k >> 3) & 3) << 4) | cl)) * 8 + (k & 7); }
            { const int k = 4 + cell;
              aX1h1[mi][nh] = (((k >> 5) * 2 + nh) * 64 + ((((k >> 3) & 3) << 4) | cl)) * 8 + (k & 7); }
            { const int k = 104 + cell;
              aX1h2[mi][nh] = (((k >> 5) * 2 + nh) * 64 + ((((k >> 3) & 3) << 4) | cl)) * 8 + (k & 7); }
        }
    }
    __syncthreads();   // weight fill visible

    // ones column for L1 bias (k=0 -> kt0, kq=0, e=0, cols 0..15, both nh) -- BOTH buffers
    if (tid < 32) {
        const int off = (((tid >> 4)) * 64 + (tid & 15)) * 8 + 0;
        X1[off] = (short)0x3F80;
        X1[X1BUF + off] = (short)0x3F80;
    }
    // x(0) -> X0 buf0; nh = w (waves 0,1); writes ONLY k=0..17 of kt0
    if (w < 2) {
        const int b = bh * 32 + w * 16 + cl;
        const float* xr = x + ((size_t)b * TT + 0) * (NN * FF) + n * FF;
        if (q < 2) {
            short8v pv;
            #pragma unroll
            for (int e = 0; e < 8; ++e) pv[e] = f2bf(xr[q * 8 + e]);
            *(short8v*)(X0 + ((size_t)w * 64 + lane) * 8) = pv;
        } else if (q == 2) {
            const unsigned lo = (unsigned short)f2bf(xr[16]);
            *(unsigned*)(X0 + ((size_t)w * 64 + lane) * 8) = (0x3F80u << 16) | lo;  // k16=x, k17=1.0
        }
    }
    __syncthreads();

    float c1[3][2], c2[3][2], macc[3][2];
    #pragma unroll
    for (int mi = 0; mi < 3; ++mi)
        #pragma unroll
        for (int nh = 0; nh < 2; ++nh) { c1[mi][nh] = 0.f; c2[mi][nh] = 0.f; macc[mi][nh] = 0.f; }

    // ---- skewed loop (R11-proven dataflow): iter i = L0(step i, i<TT) + L1(step i-1, i>0).
    //      ALL reads from [rb], ALL writes to [wb]; ONE barrier/iter.
    //      acc0/acc1 separate so L0 and L1 streams have no register dependency.
    for (int i = 0; i <= TT; ++i) {
        const int rb = i & 1;
        const int wb = rb ^ 1;
        float4v acc0[3][2], acc1[3][2];

        const bool doL0 = (i < TT);
        const bool doL1 = (i > 0);

        // ---- early issue: x(i+1) global loads into regs ----
        float xv0 = 0.f, xv1 = 0.f, xv2 = 0.f, xv3 = 0.f, xv4 = 0.f, xv5 = 0.f, xv6 = 0.f, xv7 = 0.f;
        const bool doX = doL0 && (w < 2) && (i + 1 < TT);
        if (doX) {
            const int b = bh * 32 + w * 16 + cl;
            const float* xr = x + ((size_t)b * TT + (i + 1)) * (NN * FF) + n * FF;
            if (q < 2) {
                const int k0 = q * 8;
                xv0 = xr[k0 + 0]; xv1 = xr[k0 + 1]; xv2 = xr[k0 + 2]; xv3 = xr[k0 + 3];
                xv4 = xr[k0 + 4]; xv5 = xr[k0 + 5]; xv6 = xr[k0 + 6]; xv7 = xr[k0 + 7];
            } else if (q == 2) {
                xv0 = xr[16];
            }
        }

        // ---- L0 MFMA: reads X0[rb] (x(i), h1(i-1)), A from Al ----
        if (doL0) {
            #pragma unroll
            for (int mi = 0; mi < 3; ++mi) { acc0[mi][0] = (float4v){0,0,0,0}; acc0[mi][1] = (float4v){0,0,0,0}; }
            const short* X0r = X0 + rb * X0BUF;
            #pragma unroll
            for (int kt = 0; kt < 4; ++kt) {
                const short8v b0 = *(const short8v*)(X0r + (((size_t)kt * 2 + 0) * 64 + lane) * 8);
                const short8v b1 = *(const short8v*)(X0r + (((size_t)kt * 2 + 1) * 64 + lane) * 8);
                #pragma unroll
                for (int mi = 0; mi < 3; ++mi) {
                    if (mi < nmt) {
                        const short8v a = *(const short8v*)(
                            Al + (((size_t)kt * NMT + (mt0 + mi)) * 64 + lane) * 8);
                        acc0[mi][0] = __builtin_amdgcn_mfma_f32_16x16x32_bf16(a, b0, acc0[mi][0], 0, 0, 0);
                        acc0[mi][1] = __builtin_amdgcn_mfma_f32_16x16x32_bf16(a, b1, acc0[mi][1], 0, 0, 0);
                    }
                }
            }
        }

        // ---- L1 MFMA for step t=i-1: reads X1[rb] (ones, h1(i-1), h2(i-2)), A from wr1 / B24l ----
        if (doL1) {
            #pragma unroll
            for (int mi = 0; mi < 3; ++mi) { acc1[mi][0] = (float4v){0,0,0,0}; acc1[mi][1] = (float4v){0,0,0,0}; }
            const short* X1r = X1 + rb * X1BUF;
            #pragma unroll
            for (int kt = 0; kt < 7; ++kt) {
                const short8v b0 = *(const short8v*)(X1r + (((size_t)kt * 2 + 0) * 64 + lane) * 8);
                const short8v b1 = *(const short8v*)(X1r + (((size_t)kt * 2 + 1) * 64 + lane) * 8);
                #pragma unroll
                for (int mi = 0; mi < 2; ++mi) {
                    acc1[mi][0] = __builtin_amdgcn_mfma_f32_16x16x32_bf16(wr1[mi][kt], b0, acc1[mi][0], 0, 0, 0);
                    acc1[mi][1] = __builtin_amdgcn_mfma_f32_16x16x32_bf16(wr1[mi][kt], b1, acc1[mi][1], 0, 0, 0);
                }
                if (w11) {
                    const short8v a = *(const short8v*)(B24l + ((size_t)kt * 64 + lane) * 8);
                    acc1[2][0] = __builtin_amdgcn_mfma_f32_16x16x32_bf16(a, b0, acc1[2][0], 0, 0, 0);
                    acc1[2][1] = __builtin_amdgcn_mfma_f32_16x16x32_bf16(a, b1, acc1[2][1], 0, 0, 0);
                }
            }
        }

        // ---- L0 act: h1(i) -> X0[wb].h1, X1[wb].h1 ----
        if (doL0) {
            const bool fin0 = (i == TT - 1);
            #pragma unroll
            for (int mi = 0; mi < 3; ++mi) {
                if (mi < nmt) {
                    const int cell = (mt0 + mi) * 4 + q;
                    #pragma unroll
                    for (int nh = 0; nh < 2; ++nh) {
                        const float iv = sigm_(acc0[mi][nh][0]);
                        const float fv = sigm_(acc0[mi][nh][1]);
                        const float gv = tanh_(acc0[mi][nh][2]);
                        const float ov = sigm_(acc0[mi][nh][3]);
                        const float c  = fv * c1[mi][nh] + iv * gv;
                        c1[mi][nh] = c;
                        const float h = ov * tanh_(c);
                        const short hb = f2bf(h);
                        X0[wb * X0BUF + aX0h1[mi][nh]] = hb;   // h1(i) for iter i+1's L0
                        X1[wb * X1BUF + aX1h1[mi][nh]] = hb;   // h1(i) for iter i+1's L1
                        if (fin0) {
                            const int b = bh * 32 + nh * 16 + cl;
                            out[8064 + ((size_t)(n * 2 + 0) * 64 + b) * HH + cell] = h;
                            out[8064 + 1612800 + ((size_t)(n * 2 + 0) * 64 + b) * HH + cell] = c;
                        }
                    }
                }
            }
            // write x(i+1) into X0[wb] kt0, nh = w
            if (doX) {
                short* X0w = X0 + wb * X0BUF;
                if (q < 2) {
                    short8v pv;
                    pv[0] = f2bf(xv0); pv[1] = f2bf(xv1); pv[2] = f2bf(xv2); pv[3] = f2bf(xv3);
                    pv[4] = f2bf(xv4); pv[5] = f2bf(xv5); pv[6] = f2bf(xv6); pv[7] = f2bf(xv7);
                    *(short8v*)(X0w + ((size_t)w * 64 + lane) * 8) = pv;
                } else if (q == 2) {
                    const unsigned lo = (unsigned short)f2bf(xv0);
                    *(unsigned*)(X0w + ((size_t)w * 64 + lane) * 8) = (0x3F80u << 16) | lo;
                }
            }
        }

        // ---- L1 act: h2(i-1) -> X1[wb].h2; macc; fin at i==TT ----
        if (doL1) {
            const float wet = wend[i - 1];
            const bool fin1 = (i == TT);
            #pragma unroll
            for (int mi = 0; mi < 3; ++mi) {
                if (mi < nmt) {
                    const int cell = (mt0 + mi) * 4 + q;
                    #pragma unroll
                    for (int nh = 0; nh < 2; ++nh) {
                        const float iv = sigm_(acc1[mi][nh][0]);
                        const float fv = sigm_(acc1[mi][nh][1]);
                        const float gv = tanh_(acc1[mi][nh][2]);
                        const float ov = sigm_(acc1[mi][nh][3]);
                        const float c  = fv * c2[mi][nh] + iv * gv;
                        c2[mi][nh] = c;
                        const float h = ov * tanh_(c);
                        macc[mi][nh] = fmaf(wet, h, macc[mi][nh]);
                        if (!fin1) X1[wb * X1BUF + aX1h2[mi][nh]] = f2bf(h);   // h2(i-1) for iter i+1's L1
                        if (fin1) {
                            const int b = bh * 32 + nh * 16 + cl;
                            out[8064 + ((size_t)(n * 2 + 1) * 64 + b) * HH + cell] = h;
                            out[8064 + 1612800 + ((size_t)(n * 2 + 1) * 64 + b) * HH + cell] = c;
                        }
                    }
                }
            }
        }
        __syncthreads();   // single barrier: [wb] writes visible; [rb] reads drained
    }

    // -------- epilogue: out[b,0,n,0] (red overlays Al) --------
    #pragma unroll
    for (int mi = 0; mi < 3; ++mi) {
        if (mi < nmt) {
            const int cell = (mt0 + mi) * 4 + q;
            #pragma unroll
            for (int nh = 0; nh < 2; ++nh)
                red[cell * 32 + nh * 16 + cl] = wlin[cell] * macc[mi][nh];
        }
    }
    __syncthreads();
    if (tid < 32) {
        float s = 0.0f;
        for (int j = 0; j < HH; ++j) s += red[j * 32 + tid];
        float ws = 0.0f;
        for (int t2 = 0; t2 < TT; ++t2) ws += wend[t2];
        s += blin[0] * ws + bend[0];
        out[(size_t)(bh * 32 + tid) * NN + n] = s;
    }
}

extern "C" void kernel_launch(void* const* d_in, const int* in_sizes, int n_in,
                              void* d_out, int out_size, void* d_ws, size_t ws_size,
                              hipStream_t stream) {
    const float* x    = (const float*)d_in[0];
    const float* Wih0 = (const float*)d_in[1];
    const float* Whh0 = (const float*)d_in[2];
    const float* bih0 = (const float*)d_in[3];
    const float* bhh0 = (const float*)d_in[4];
    const float* Wih1 = (const float*)d_in[5];
    const float* Whh1 = (const float*)d_in[6];
    const float* bih1 = (const float*)d_in[7];
    const float* bhh1 = (const float*)d_in[8];
    const float* wlin = (const float*)d_in[9];
    const float* blin = (const float*)d_in[10];
    const float* wend = (const float*)d_in[11];
    const float* bend = (const float*)d_in[12];
    (void)d_ws; (void)ws_size; (void)in_sizes; (void)n_in; (void)out_size;

    lstm_o12<<<dim3(NN * 2), dim3(NTH), LDS_BYTES, stream>>>(
        x, Wih0, Whh0, bih0, bhh0, Wih1, Whh1, bih1, bhh1,
        wlin, blin, wend, bend, (float*)d_out);
}

// Round 14
// 110.135 us; speedup vs baseline: 1.4838x; 1.4838x over previous
//
#include <hip/hip_runtime.h>
#include <hip/hip_bf16.h>

#define NN 126   // nodes
#define TT 24    // seq len
#define FF 17    // input feat
#define HH 100   // hidden
#define NMT 25   // M tiles (400 gate-interleaved rows)

// ---------- MFMA fragment geometry (identical to R10) ----------
//  L0, kt 0..3  (K=128): k<17 Wih0 | k==17 bias0 | k=18+j Whh0 (j<100) | pad 118..127
//  L1, kt 0..6  (K=224): k==0 bias1(ones col) | pad 1..3 | k=4+j Wih1 | k=104+j Whh1 | pad 204..223
// LDS layout in shorts: Al[4][25][64][8]=51200 | X0[2buf][4kt][2nh][64][8]=8192 | X1[2buf][7kt][2nh][64][8]=14336
#define AL_SH 51200
#define X0_SH AL_SH
#define X1_SH (AL_SH + 8192)
#define X0BUF 4096
#define X1BUF 7168
#define TOT_SH (X1_SH + 2 * X1BUF)     // 73728 shorts
#define LDS_BYTES (TOT_SH * 2)         // 147,456 B

// zero range: Al kt3 (pad tail lives there) + X0 + X1 = contiguous [38400, 73728)
#define ZERO_BASE 38400
#define ZERO_SH   (TOT_SH - ZERO_BASE) // 35328 shorts

typedef __attribute__((ext_vector_type(8))) short short8v;
typedef __attribute__((ext_vector_type(4))) float float4v;

__device__ __forceinline__ short f2bf(float f) {
    union { float f; unsigned u; } v; v.f = f;
    unsigned r = v.u + 0x7FFFu + ((v.u >> 16) & 1u);   // RNE
    return (short)(r >> 16);
}
#define LOG2E 1.4426950408889634f
__device__ __forceinline__ float sigm_(float x) {
    return __builtin_amdgcn_rcpf(1.0f + __builtin_amdgcn_exp2f(-LOG2E * x));
}
__device__ __forceinline__ float tanh_(float x) {
    return 1.0f - 2.0f * __builtin_amdgcn_rcpf(1.0f + __builtin_amdgcn_exp2f((2.0f * LOG2E) * x));
}

// ---------------- fused: prep + 16-wave 2-barrier double-buffered MFMA LSTM ----------------
__global__ __launch_bounds__(1024, 4)
void lstm_one(const float* __restrict__ x,
              const float* __restrict__ Wih0, const float* __restrict__ Whh0,
              const float* __restrict__ bih0, const float* __restrict__ bhh0,
              const float* __restrict__ Wih1, const float* __restrict__ Whh1,
              const float* __restrict__ bih1, const float* __restrict__ bhh1,
              const float* __restrict__ wlin, const float* __restrict__ blin,
              const float* __restrict__ wend, const float* __restrict__ bend,
              float* __restrict__ out)
{
    extern __shared__ short lds_s[];
    short* Al = lds_s;                 // L0 weights [kt][mt][lane][e]
    short* X0 = lds_s + X0_SH;         // [buf][kt][nh][lane][e]
    short* X1 = lds_s + X1_SH;         // [buf][kt][nh][lane][e]; h1/ones only in buf0
    float* red = (float*)lds_s;        // overlay over Al, epilogue only

    const int n   = blockIdx.x >> 1;
    const int bh  = blockIdx.x & 1;                 // batch half (32 each)
    const int tid = threadIdx.x, lane = tid & 63, w = tid >> 6;   // 16 waves
    const int cl  = lane & 15, q = lane >> 4;
    const int mt0 = (w <= 8) ? (w * 2) : (18 + (w - 9));  // waves 0..8: 2 tiles; 9..15: 1
    const int nmt = (w <= 8) ? 2 : 1;

    // ---- init 0: zero only the regions that need zeros (Al kt3 pad + X0 + X1) ----
    {
        const short8v zz = {0,0,0,0,0,0,0,0};
        for (int i = tid; i < ZERO_SH / 8; i += 1024)
            *(short8v*)(lds_s + ZERO_BASE + (size_t)i * 8) = zz;
    }
    __syncthreads();   // zeros visible before scatter-fill

    // ---- init 1: L0 weights -> Al (fp32 float4 read, bf16 LDS scatter) ----
    {
        // Whh0 row = 100 floats = exactly 25 float4s -> no row crossing
        const float4v* W4 = (const float4v*)(Whh0 + (size_t)n * 40000);
        for (int i = tid; i < 10000; i += 1024) {
            const int orl = i / 25, jq = i - orl * 25;
            const int g = orl / 100, cell = orl - g * 100;
            const int gr = cell * 4 + g;
            const float4v v = W4[i];
            #pragma unroll
            for (int e4 = 0; e4 < 4; ++e4) {
                const int k = 18 + jq * 4 + e4;   // k = 18+j
                Al[(((k >> 5) * NMT + (gr >> 4)) * 64 + ((((k >> 3) & 3) << 4) | (gr & 15))) * 8 + (k & 7)]
                    = f2bf(v[e4]);
            }
        }
    }
    {
        const float* W = Wih0 + (size_t)n * 6800;         // [orl][k 0..16], kt0
        for (int i = tid; i < 6800; i += 1024) {
            const int orl = i / 17, k = i - orl * 17;
            const int g = orl / 100, cell = orl - g * 100;
            const int gr = cell * 4 + g;
            Al[((gr >> 4) * 64 + ((((k >> 3) & 3) << 4) | (gr & 15))) * 8 + (k & 7)] = f2bf(W[i]);
        }
    }
    if (tid < 400) {                                      // L0 bias at k=17 (kt0, kq2, e1)
        const int g = tid / 100, cell = tid - g * 100;
        const int gr = cell * 4 + g;
        const int orow = n * 400 + tid;
        Al[((gr >> 4) * 64 + ((2 << 4) | (gr & 15))) * 8 + 1] = f2bf(bih0[orow] + bhh0[orow]);
    }

    // ---- init 2: L1 weights -> wreg (per-thread contiguous 32B gathers) ----
    short8v wreg[2][7];
    #pragma unroll
    for (int mi = 0; mi < 2; ++mi) {
        if (mi < nmt) {
            const int gr = (mt0 + mi) * 16 + cl;
            const int cell = gr >> 2, g = gr & 3;
            const int orow = n * 400 + g * HH + cell;
            const float* Wi = Wih1 + (size_t)orow * HH;
            const float* Wh = Whh1 + (size_t)orow * HH;
            #pragma unroll
            for (int kt = 0; kt < 7; ++kt) {
                const int k0 = kt * 32 + q * 8;           // chunk base, multiple of 8
                float v[8];
                #pragma unroll
                for (int e = 0; e < 8; ++e) v[e] = 0.0f;
                if (k0 == 0) {                            // mixed: bias | pad | Wih1 j0..3
                    v[0] = bih1[orow] + bhh1[orow];
                    v[4] = Wi[0]; v[5] = Wi[1]; v[6] = Wi[2]; v[7] = Wi[3];
                } else if (k0 <= 96) {                    // pure Wih1, j = k0-4+e
                    #pragma unroll
                    for (int e = 0; e < 8; ++e) v[e] = Wi[k0 - 4 + e];
                } else if (k0 >= 104 && k0 <= 192) {      // pure Whh1, j = k0-104+e
                    #pragma unroll
                    for (int e = 0; e < 8; ++e) v[e] = Wh[k0 - 104 + e];
                } else if (k0 == 200) {                   // mixed: Whh1 j96..99 | pad
                    v[0] = Wh[96]; v[1] = Wh[97]; v[2] = Wh[98]; v[3] = Wh[99];
                }
                short8v pv;
                #pragma unroll
                for (int e = 0; e < 8; ++e) pv[e] = f2bf(v[e]);
                wreg[mi][kt] = pv;
            }
        }
    }

    // hoisted per-thread LDS scatter element-offsets (within a buffer)
    int aX0h1[2][2], aX1h1[2][2], aX1h2[2][2];
    #pragma unroll
    for (int mi = 0; mi < 2; ++mi) {
        const int cell = (mt0 + mi) * 4 + q;
        #pragma unroll
        for (int nh = 0; nh < 2; ++nh) {
            { const int k = 18 + cell;
              aX0h1[mi][nh] = (((k >> 5) * 2 + nh) * 64 + ((((k >> 3) & 3) << 4) | cl)) * 8 + (k & 7); }
            { const int k = 4 + cell;
              aX1h1[mi][nh] = (((k >> 5) * 2 + nh) * 64 + ((((k >> 3) & 3) << 4) | cl)) * 8 + (k & 7); }
            { const int k = 104 + cell;
              aX1h2[mi][nh] = (((k >> 5) * 2 + nh) * 64 + ((((k >> 3) & 3) << 4) | cl)) * 8 + (k & 7); }
        }
    }
    __syncthreads();   // weight fill visible

    // ones column for L1 bias (k=0 -> kt0, kq=0, e=0, cols 0..15, both nh) -- buf0 only
    if (tid < 32) X1[(((tid >> 4)) * 64 + (tid & 15)) * 8 + 0] = (short)0x3F80;
    // x(0) -> X0 buf0 directly from global; nh = w; writes ONLY k=0..17 of kt0
    if (w < 2) {
        const int b = bh * 32 + w * 16 + cl;
        const float* xr = x + ((size_t)b * TT + 0) * (NN * FF) + n * FF;
        if (q < 2) {
            short8v pv;
            #pragma unroll
            for (int e = 0; e < 8; ++e) pv[e] = f2bf(xr[q * 8 + e]);
            *(short8v*)(X0 + ((size_t)w * 64 + lane) * 8) = pv;            // nh = w
        } else if (q == 2) {
            const unsigned lo = (unsigned short)f2bf(xr[16]);
            *(unsigned*)(X0 + ((size_t)w * 64 + lane) * 8) = (0x3F80u << 16) | lo;  // k16=x, k17=1.0
        }
    }
    __syncthreads();

    float c1[2][2], c2[2][2], macc[2][2];
    #pragma unroll
    for (int mi = 0; mi < 2; ++mi)
        #pragma unroll
        for (int nh = 0; nh < 2; ++nh) { c1[mi][nh] = 0.f; c2[mi][nh] = 0.f; macc[mi][nh] = 0.f; }

    for (int t = 0; t < TT; ++t) {
        const bool fin = (t == TT - 1);
        const int rb = t & 1;                  // read buffer (X0 full; X1.h2)
        const int wb = rb ^ 1;                 // write buffer
        float4v acc[2][2];

        // ======== PHASE A: L0 MFMA (reads X0[rb], Al) + L0 act (writes X0[wb].h1, X1[0].h1) ========
        #pragma unroll
        for (int mi = 0; mi < 2; ++mi) { acc[mi][0] = (float4v){0,0,0,0}; acc[mi][1] = (float4v){0,0,0,0}; }
        {
            const short* X0r = X0 + rb * X0BUF;
            #pragma unroll
            for (int kt = 0; kt < 4; ++kt) {
                const short8v b0 = *(const short8v*)(X0r + (((size_t)kt * 2 + 0) * 64 + lane) * 8);
                const short8v b1 = *(const short8v*)(X0r + (((size_t)kt * 2 + 1) * 64 + lane) * 8);
                #pragma unroll
                for (int mi = 0; mi < 2; ++mi) {
                    if (mi < nmt) {
                        const short8v a = *(const short8v*)(
                            Al + (((size_t)kt * NMT + (mt0 + mi)) * 64 + lane) * 8);
                        acc[mi][0] = __builtin_amdgcn_mfma_f32_16x16x32_bf16(a, b0, acc[mi][0], 0, 0, 0);
                        acc[mi][1] = __builtin_amdgcn_mfma_f32_16x16x32_bf16(a, b1, acc[mi][1], 0, 0, 0);
                    }
                }
            }
        }
        #pragma unroll
        for (int mi = 0; mi < 2; ++mi) {
            if (mi < nmt) {
                const int cell = (mt0 + mi) * 4 + q;
                #pragma unroll
                for (int nh = 0; nh < 2; ++nh) {
                    const float iv = sigm_(acc[mi][nh][0]);
                    const float fv = sigm_(acc[mi][nh][1]);
                    const float gv = tanh_(acc[mi][nh][2]);
                    const float ov = sigm_(acc[mi][nh][3]);
                    const float c  = fv * c1[mi][nh] + iv * gv;
                    c1[mi][nh] = c;
                    const float h = ov * tanh_(c);
                    const short hb = f2bf(h);
                    X0[wb * X0BUF + aX0h1[mi][nh]] = hb;   // h1(t) for next step's L0
                    X1[aX1h1[mi][nh]] = hb;                // h1(t) for this step's L1 (buf0)
                    if (fin) {
                        const int b = bh * 32 + nh * 16 + cl;
                        out[8064 + ((size_t)(n * 2 + 0) * 64 + b) * HH + cell] = h;
                        out[8064 + 1612800 + ((size_t)(n * 2 + 0) * 64 + b) * HH + cell] = c;
                    }
                }
            }
        }
        __syncthreads();   // BARRIER 1: h1(t) visible

        // early issue: x(t+1) global loads into regs (written to LDS after L1 act)
        float xv0 = 0.f, xv1 = 0.f, xv2 = 0.f, xv3 = 0.f, xv4 = 0.f, xv5 = 0.f, xv6 = 0.f, xv7 = 0.f;
        const bool doX = (w < 2) && (t + 1 < TT);
        if (doX) {
            const int b = bh * 32 + w * 16 + cl;
            const float* xr = x + ((size_t)b * TT + (t + 1)) * (NN * FF) + n * FF;
            if (q < 2) {
                const int k0 = q * 8;
                xv0 = xr[k0 + 0]; xv1 = xr[k0 + 1]; xv2 = xr[k0 + 2]; xv3 = xr[k0 + 3];
                xv4 = xr[k0 + 4]; xv5 = xr[k0 + 5]; xv6 = xr[k0 + 6]; xv7 = xr[k0 + 7];
            } else if (q == 2) {
                xv0 = xr[16];
            }
        }

        // ======== PHASE B: L1 MFMA (reads X1[0].h1, X1[rb].h2) + L1 act (writes X1[wb].h2) ========
        #pragma unroll
        for (int mi = 0; mi < 2; ++mi) { acc[mi][0] = (float4v){0,0,0,0}; acc[mi][1] = (float4v){0,0,0,0}; }
        {
            const short* X1h2 = X1 + rb * X1BUF;
            const int kt3sel = (q == 0) ? 0 : rb * X1BUF;   // kt3: kq0 = h1 (buf0), kq1-3 = h2 (rb)
            #pragma unroll
            for (int kt = 0; kt < 7; ++kt) {
                const short* base = (kt < 3) ? X1 : ((kt == 3) ? (X1 + kt3sel) : X1h2);
                const short8v b0 = *(const short8v*)(base + (((size_t)kt * 2 + 0) * 64 + lane) * 8);
                const short8v b1 = *(const short8v*)(base + (((size_t)kt * 2 + 1) * 64 + lane) * 8);
                #pragma unroll
                for (int mi = 0; mi < 2; ++mi) {
                    if (mi < nmt) {
                        acc[mi][0] = __builtin_amdgcn_mfma_f32_16x16x32_bf16(wreg[mi][kt], b0, acc[mi][0], 0, 0, 0);
                        acc[mi][1] = __builtin_amdgcn_mfma_f32_16x16x32_bf16(wreg[mi][kt], b1, acc[mi][1], 0, 0, 0);
                    }
                }
            }
        }
        const float wet = wend[t];
        #pragma unroll
        for (int mi = 0; mi < 2; ++mi) {
            if (mi < nmt) {
                const int cell = (mt0 + mi) * 4 + q;
                #pragma unroll
                for (int nh = 0; nh < 2; ++nh) {
                    const float iv = sigm_(acc[mi][nh][0]);
                    const float fv = sigm_(acc[mi][nh][1]);
                    const float gv = tanh_(acc[mi][nh][2]);
                    const float ov = sigm_(acc[mi][nh][3]);
                    const float c  = fv * c2[mi][nh] + iv * gv;
                    c2[mi][nh] = c;
                    const float h = ov * tanh_(c);
                    macc[mi][nh] = fmaf(wet, h, macc[mi][nh]);
                    if (!fin) X1[wb * X1BUF + aX1h2[mi][nh]] = f2bf(h);   // h2(t) -> write buf
                    if (fin) {
                        const int b = bh * 32 + nh * 16 + cl;
                        out[8064 + ((size_t)(n * 2 + 1) * 64 + b) * HH + cell] = h;
                        out[8064 + 1612800 + ((size_t)(n * 2 + 1) * 64 + b) * HH + cell] = c;
                    }
                }
            }
        }
        // write x(t+1) into X0[wb] kt0, nh = w (k0..17 only; h1(t) already at k>=18 of wb)
        if (doX) {
            short* X0w = X0 + wb * X0BUF;
            if (q < 2) {
                short8v pv;
                pv[0] = f2bf(xv0); pv[1] = f2bf(xv1); pv[2] = f2bf(xv2); pv[3] = f2bf(xv3);
                pv[4] = f2bf(xv4); pv[5] = f2bf(xv5); pv[6] = f2bf(xv6); pv[7] = f2bf(xv7);
                *(short8v*)(X0w + ((size_t)w * 64 + lane) * 8) = pv;       // nh = w
            } else if (q == 2) {
                const unsigned lo = (unsigned short)f2bf(xv0);
                *(unsigned*)(X0w + ((size_t)w * 64 + lane) * 8) = (0x3F80u << 16) | lo;
            }
        }
        __syncthreads();   // BARRIER 2: h2(t) / x(t+1) visible
    }

    // -------- epilogue: out[b,0,n,0] (red overlays Al) --------
    #pragma unroll
    for (int mi = 0; mi < 2; ++mi) {
        if (mi < nmt) {
            const int cell = (mt0 + mi) * 4 + q;
            #pragma unroll
            for (int nh = 0; nh < 2; ++nh)
                red[cell * 32 + nh * 16 + cl] = wlin[cell] * macc[mi][nh];
        }
    }
    __syncthreads();
    if (tid < 32) {
        float s = 0.0f;
        for (int j = 0; j < HH; ++j) s += red[j * 32 + tid];
        float ws = 0.0f;
        for (int t2 = 0; t2 < TT; ++t2) ws += wend[t2];
        s += blin[0] * ws + bend[0];
        out[(size_t)(bh * 32 + tid) * NN + n] = s;
    }
}

extern "C" void kernel_launch(void* const* d_in, const int* in_sizes, int n_in,
                              void* d_out, int out_size, void* d_ws, size_t ws_size,
                              hipStream_t stream) {
    const float* x    = (const float*)d_in[0];
    const float* Wih0 = (const float*)d_in[1];
    const float* Whh0 = (const float*)d_in[2];
    const float* bih0 = (const float*)d_in[3];
    const float* bhh0 = (const float*)d_in[4];
    const float* Wih1 = (const float*)d_in[5];
    const float* Whh1 = (const float*)d_in[6];
    const float* bih1 = (const float*)d_in[7];
    const float* bhh1 = (const float*)d_in[8];
    const float* wlin = (const float*)d_in[9];
    const float* blin = (const float*)d_in[10];
    const float* wend = (const float*)d_in[11];
    const float* bend = (const float*)d_in[12];
    (void)d_ws; (void)ws_size; (void)in_sizes; (void)n_in; (void)out_size;

    lstm_one<<<dim3(NN * 2), dim3(1024), LDS_BYTES, stream>>>(
        x, Wih0, Whh0, bih0, bhh0, Wih1, Whh1, bih1, bhh1,
        wlin, blin, wend, bend, (float*)d_out);
}

// Round 15
// 107.394 us; speedup vs baseline: 1.5216x; 1.0255x over previous
//
#include <hip/hip_runtime.h>
#include <hip/hip_bf16.h>

#define NN 126   // nodes
#define TT 24    // seq len
#define FF 17    // input feat
#define HH 100   // hidden
#define NMT 25   // M tiles (400 gate-interleaved rows)

// ---------- MFMA fragment geometry (identical to R10/R14) ----------
//  L0, kt 0..3  (K=128): k<17 Wih0 | k==17 bias0 | k=18+j Whh0 (j<100) | pad 118..127
//  L1, kt 0..6  (K=224): k==0 bias1(ones col) | pad 1..3 | k=4+j Wih1 | k=104+j Whh1 | pad 204..223
// LDS layout in shorts: Al[4][25][64][8]=51200 | X0[2buf][4kt][2nh][64][8]=8192 | X1[2buf][7kt][2nh][64][8]=14336
#define AL_SH 51200
#define X0_SH AL_SH
#define X1_SH (AL_SH + 8192)
#define X0BUF 4096
#define X1BUF 7168
#define TOT_SH (X1_SH + 2 * X1BUF)     // 73728 shorts
#define LDS_BYTES (TOT_SH * 2)         // 147,456 B

// zero range: Al kt3 (pad tail lives there) + X0 + X1 = contiguous [38400, 73728)
#define ZERO_BASE 38400
#define ZERO_SH   (TOT_SH - ZERO_BASE) // 35328 shorts

typedef __attribute__((ext_vector_type(8))) short short8v;
typedef __attribute__((ext_vector_type(4))) float float4v;

__device__ __forceinline__ short f2bf(float f) {
    union { float f; unsigned u; } v; v.f = f;
    unsigned r = v.u + 0x7FFFu + ((v.u >> 16) & 1u);   // RNE
    return (short)(r >> 16);
}
#define LOG2E 1.4426950408889634f
__device__ __forceinline__ float sigm_(float x) {
    return __builtin_amdgcn_rcpf(1.0f + __builtin_amdgcn_exp2f(-LOG2E * x));
}
// fused sigma(a)*tanh(b) = (1-B) / ((1+B)(1+A)),  A=exp2(-a*log2e), B=exp2(-2b*log2e)
// one rcp instead of two; overflow-safe for |a|,|b| < ~40 (gates ~<10, |c| <= 24)
__device__ __forceinline__ float sigtanh(float a, float b) {
    const float A = __builtin_amdgcn_exp2f(-LOG2E * a);
    const float B = __builtin_amdgcn_exp2f(-(2.0f * LOG2E) * b);
    return (1.0f - B) * __builtin_amdgcn_rcpf((1.0f + B) * (1.0f + A));
}

// ---------------- fused: prep + 16-wave 2-barrier double-buffered MFMA LSTM ----------------
__global__ __launch_bounds__(1024, 4)
void lstm_one(const float* __restrict__ x,
              const float* __restrict__ Wih0, const float* __restrict__ Whh0,
              const float* __restrict__ bih0, const float* __restrict__ bhh0,
              const float* __restrict__ Wih1, const float* __restrict__ Whh1,
              const float* __restrict__ bih1, const float* __restrict__ bhh1,
              const float* __restrict__ wlin, const float* __restrict__ blin,
              const float* __restrict__ wend, const float* __restrict__ bend,
              float* __restrict__ out)
{
    extern __shared__ short lds_s[];
    short* Al = lds_s;                 // L0 weights [kt][mt][lane][e]
    short* X0 = lds_s + X0_SH;         // [buf][kt][nh][lane][e]
    short* X1 = lds_s + X1_SH;         // [buf][kt][nh][lane][e]; h1/ones only in buf0
    float* red = (float*)lds_s;        // overlay over Al, epilogue only

    const int n   = blockIdx.x >> 1;
    const int bh  = blockIdx.x & 1;                 // batch half (32 each)
    const int tid = threadIdx.x, lane = tid & 63, w = tid >> 6;   // 16 waves
    const int cl  = lane & 15, q = lane >> 4;
    const int mt0 = (w <= 8) ? (w * 2) : (18 + (w - 9));  // waves 0..8: 2 tiles; 9..15: 1
    const int nmt = (w <= 8) ? 2 : 1;

    // ---- init 0: zero only the regions that need zeros (Al kt3 pad + X0 + X1) ----
    {
        const short8v zz = {0,0,0,0,0,0,0,0};
        for (int i = tid; i < ZERO_SH / 8; i += 1024)
            *(short8v*)(lds_s + ZERO_BASE + (size_t)i * 8) = zz;
    }
    __syncthreads();   // zeros visible before scatter-fill

    // ---- init 1: L0 weights -> Al (fp32 float4 read, bf16 LDS scatter) ----
    {
        // Whh0 row = 100 floats = exactly 25 float4s -> no row crossing
        const float4v* W4 = (const float4v*)(Whh0 + (size_t)n * 40000);
        for (int i = tid; i < 10000; i += 1024) {
            const int orl = i / 25, jq = i - orl * 25;
            const int g = orl / 100, cell = orl - g * 100;
            const int gr = cell * 4 + g;
            const float4v v = W4[i];
            #pragma unroll
            for (int e4 = 0; e4 < 4; ++e4) {
                const int k = 18 + jq * 4 + e4;   // k = 18+j
                Al[(((k >> 5) * NMT + (gr >> 4)) * 64 + ((((k >> 3) & 3) << 4) | (gr & 15))) * 8 + (k & 7)]
                    = f2bf(v[e4]);
            }
        }
    }
    {
        const float* W = Wih0 + (size_t)n * 6800;         // [orl][k 0..16], kt0
        for (int i = tid; i < 6800; i += 1024) {
            const int orl = i / 17, k = i - orl * 17;
            const int g = orl / 100, cell = orl - g * 100;
            const int gr = cell * 4 + g;
            Al[((gr >> 4) * 64 + ((((k >> 3) & 3) << 4) | (gr & 15))) * 8 + (k & 7)] = f2bf(W[i]);
        }
    }
    if (tid < 400) {                                      // L0 bias at k=17 (kt0, kq2, e1)
        const int g = tid / 100, cell = tid - g * 100;
        const int gr = cell * 4 + g;
        const int orow = n * 400 + tid;
        Al[((gr >> 4) * 64 + ((2 << 4) | (gr & 15))) * 8 + 1] = f2bf(bih0[orow] + bhh0[orow]);
    }

    // ---- init 2: L1 weights -> wreg (per-thread contiguous 32B gathers) ----
    short8v wreg[2][7];
    #pragma unroll
    for (int mi = 0; mi < 2; ++mi) {
        if (mi < nmt) {
            const int gr = (mt0 + mi) * 16 + cl;
            const int cell = gr >> 2, g = gr & 3;
            const int orow = n * 400 + g * HH + cell;
            const float* Wi = Wih1 + (size_t)orow * HH;
            const float* Wh = Whh1 + (size_t)orow * HH;
            #pragma unroll
            for (int kt = 0; kt < 7; ++kt) {
                const int k0 = kt * 32 + q * 8;           // chunk base, multiple of 8
                float v[8];
                #pragma unroll
                for (int e = 0; e < 8; ++e) v[e] = 0.0f;
                if (k0 == 0) {                            // mixed: bias | pad | Wih1 j0..3
                    v[0] = bih1[orow] + bhh1[orow];
                    v[4] = Wi[0]; v[5] = Wi[1]; v[6] = Wi[2]; v[7] = Wi[3];
                } else if (k0 <= 96) {                    // pure Wih1, j = k0-4+e
                    #pragma unroll
                    for (int e = 0; e < 8; ++e) v[e] = Wi[k0 - 4 + e];
                } else if (k0 >= 104 && k0 <= 192) {      // pure Whh1, j = k0-104+e
                    #pragma unroll
                    for (int e = 0; e < 8; ++e) v[e] = Wh[k0 - 104 + e];
                } else if (k0 == 200) {                   // mixed: Whh1 j96..99 | pad
                    v[0] = Wh[96]; v[1] = Wh[97]; v[2] = Wh[98]; v[3] = Wh[99];
                }
                short8v pv;
                #pragma unroll
                for (int e = 0; e < 8; ++e) pv[e] = f2bf(v[e]);
                wreg[mi][kt] = pv;
            }
        }
    }

    // hoisted per-thread LDS scatter element-offsets (within a buffer)
    int aX0h1[2][2], aX1h1[2][2], aX1h2[2][2];
    #pragma unroll
    for (int mi = 0; mi < 2; ++mi) {
        const int cell = (mt0 + mi) * 4 + q;
        #pragma unroll
        for (int nh = 0; nh < 2; ++nh) {
            { const int k = 18 + cell;
              aX0h1[mi][nh] = (((k >> 5) * 2 + nh) * 64 + ((((k >> 3) & 3) << 4) | cl)) * 8 + (k & 7); }
            { const int k = 4 + cell;
              aX1h1[mi][nh] = (((k >> 5) * 2 + nh) * 64 + ((((k >> 3) & 3) << 4) | cl)) * 8 + (k & 7); }
            { const int k = 104 + cell;
              aX1h2[mi][nh] = (((k >> 5) * 2 + nh) * 64 + ((((k >> 3) & 3) << 4) | cl)) * 8 + (k & 7); }
        }
    }
    __syncthreads();   // weight fill visible

    // ones column for L1 bias (k=0 -> kt0, kq=0, e=0, cols 0..15, both nh) -- buf0 only
    if (tid < 32) X1[(((tid >> 4)) * 64 + (tid & 15)) * 8 + 0] = (short)0x3F80;
    // x(0) -> X0 buf0 directly from global; nh = w; writes ONLY k=0..17 of kt0
    if (w < 2) {
        const int b = bh * 32 + w * 16 + cl;
        const float* xr = x + ((size_t)b * TT + 0) * (NN * FF) + n * FF;
        if (q < 2) {
            short8v pv;
            #pragma unroll
            for (int e = 0; e < 8; ++e) pv[e] = f2bf(xr[q * 8 + e]);
            *(short8v*)(X0 + ((size_t)w * 64 + lane) * 8) = pv;            // nh = w
        } else if (q == 2) {
            const unsigned lo = (unsigned short)f2bf(xr[16]);
            *(unsigned*)(X0 + ((size_t)w * 64 + lane) * 8) = (0x3F80u << 16) | lo;  // k16=x, k17=1.0
        }
    }
    __syncthreads();

    float c1[2][2], c2[2][2], macc[2][2];
    #pragma unroll
    for (int mi = 0; mi < 2; ++mi)
        #pragma unroll
        for (int nh = 0; nh < 2; ++nh) { c1[mi][nh] = 0.f; c2[mi][nh] = 0.f; macc[mi][nh] = 0.f; }

    for (int t = 0; t < TT; ++t) {
        const bool fin = (t == TT - 1);
        const int rb = t & 1;                  // read buffer (X0 full; X1.h2)
        const int wb = rb ^ 1;                 // write buffer
        float4v acc[2][2];

        // ======== PHASE A: L0 MFMA (reads X0[rb], Al) + L0 act (writes X0[wb].h1, X1[0].h1) ========
        #pragma unroll
        for (int mi = 0; mi < 2; ++mi) { acc[mi][0] = (float4v){0,0,0,0}; acc[mi][1] = (float4v){0,0,0,0}; }
        {
            const short* X0r = X0 + rb * X0BUF;
            #pragma unroll
            for (int kt = 0; kt < 4; ++kt) {
                const short8v b0 = *(const short8v*)(X0r + (((size_t)kt * 2 + 0) * 64 + lane) * 8);
                const short8v b1 = *(const short8v*)(X0r + (((size_t)kt * 2 + 1) * 64 + lane) * 8);
                #pragma unroll
                for (int mi = 0; mi < 2; ++mi) {
                    if (mi < nmt) {
                        const short8v a = *(const short8v*)(
                            Al + (((size_t)kt * NMT + (mt0 + mi)) * 64 + lane) * 8);
                        acc[mi][0] = __builtin_amdgcn_mfma_f32_16x16x32_bf16(a, b0, acc[mi][0], 0, 0, 0);
                        acc[mi][1] = __builtin_amdgcn_mfma_f32_16x16x32_bf16(a, b1, acc[mi][1], 0, 0, 0);
                    }
                }
            }
        }
        #pragma unroll
        for (int mi = 0; mi < 2; ++mi) {
            if (mi < nmt) {
                const int cell = (mt0 + mi) * 4 + q;
                #pragma unroll
                for (int nh = 0; nh < 2; ++nh) {
                    const float ig = sigtanh(acc[mi][nh][0], acc[mi][nh][2]);  // sigma(i)*tanh(g)
                    const float fv = sigm_(acc[mi][nh][1]);
                    const float c  = fmaf(fv, c1[mi][nh], ig);
                    c1[mi][nh] = c;
                    const float h = sigtanh(acc[mi][nh][3], c);                // sigma(o)*tanh(c)
                    const short hb = f2bf(h);
                    X0[wb * X0BUF + aX0h1[mi][nh]] = hb;   // h1(t) for next step's L0
                    X1[aX1h1[mi][nh]] = hb;                // h1(t) for this step's L1 (buf0)
                    if (fin) {
                        const int b = bh * 32 + nh * 16 + cl;
                        out[8064 + ((size_t)(n * 2 + 0) * 64 + b) * HH + cell] = h;
                        out[8064 + 1612800 + ((size_t)(n * 2 + 0) * 64 + b) * HH + cell] = c;
                    }
                }
            }
        }
        __syncthreads();   // BARRIER 1: h1(t) visible

        // early issue: x(t+1) global loads into regs (written to LDS after L1 act)
        float xv0 = 0.f, xv1 = 0.f, xv2 = 0.f, xv3 = 0.f, xv4 = 0.f, xv5 = 0.f, xv6 = 0.f, xv7 = 0.f;
        const bool doX = (w < 2) && (t + 1 < TT);
        if (doX) {
            const int b = bh * 32 + w * 16 + cl;
            const float* xr = x + ((size_t)b * TT + (t + 1)) * (NN * FF) + n * FF;
            if (q < 2) {
                const int k0 = q * 8;
                xv0 = xr[k0 + 0]; xv1 = xr[k0 + 1]; xv2 = xr[k0 + 2]; xv3 = xr[k0 + 3];
                xv4 = xr[k0 + 4]; xv5 = xr[k0 + 5]; xv6 = xr[k0 + 6]; xv7 = xr[k0 + 7];
            } else if (q == 2) {
                xv0 = xr[16];
            }
        }

        // ======== PHASE B: L1 MFMA (reads X1[0].h1, X1[rb].h2) + L1 act (writes X1[wb].h2) ========
        #pragma unroll
        for (int mi = 0; mi < 2; ++mi) { acc[mi][0] = (float4v){0,0,0,0}; acc[mi][1] = (float4v){0,0,0,0}; }
        {
            const short* X1h2 = X1 + rb * X1BUF;
            const int kt3sel = (q == 0) ? 0 : rb * X1BUF;   // kt3: kq0 = h1 (buf0), kq1-3 = h2 (rb)
            #pragma unroll
            for (int kt = 0; kt < 7; ++kt) {
                const short* base = (kt < 3) ? X1 : ((kt == 3) ? (X1 + kt3sel) : X1h2);
                const short8v b0 = *(const short8v*)(base + (((size_t)kt * 2 + 0) * 64 + lane) * 8);
                const short8v b1 = *(const short8v*)(base + (((size_t)kt * 2 + 1) * 64 + lane) * 8);
                #pragma unroll
                for (int mi = 0; mi < 2; ++mi) {
                    if (mi < nmt) {
                        acc[mi][0] = __builtin_amdgcn_mfma_f32_16x16x32_bf16(wreg[mi][kt], b0, acc[mi][0], 0, 0, 0);
                        acc[mi][1] = __builtin_amdgcn_mfma_f32_16x16x32_bf16(wreg[mi][kt], b1, acc[mi][1], 0, 0, 0);
                    }
                }
            }
        }
        const float wet = wend[t];
        #pragma unroll
        for (int mi = 0; mi < 2; ++mi) {
            if (mi < nmt) {
                const int cell = (mt0 + mi) * 4 + q;
                #pragma unroll
                for (int nh = 0; nh < 2; ++nh) {
                    const float ig = sigtanh(acc[mi][nh][0], acc[mi][nh][2]);
                    const float fv = sigm_(acc[mi][nh][1]);
                    const float c  = fmaf(fv, c2[mi][nh], ig);
                    c2[mi][nh] = c;
                    const float h = sigtanh(acc[mi][nh][3], c);
                    macc[mi][nh] = fmaf(wet, h, macc[mi][nh]);
                    if (!fin) X1[wb * X1BUF + aX1h2[mi][nh]] = f2bf(h);   // h2(t) -> write buf
                    if (fin) {
                        const int b = bh * 32 + nh * 16 + cl;
                        out[8064 + ((size_t)(n * 2 + 1) * 64 + b) * HH + cell] = h;
                        out[8064 + 1612800 + ((size_t)(n * 2 + 1) * 64 + b) * HH + cell] = c;
                    }
                }
            }
        }
        // write x(t+1) into X0[wb] kt0, nh = w (k0..17 only; h1(t) already at k>=18 of wb)
        if (doX) {
            short* X0w = X0 + wb * X0BUF;
            if (q < 2) {
                short8v pv;
                pv[0] = f2bf(xv0); pv[1] = f2bf(xv1); pv[2] = f2bf(xv2); pv[3] = f2bf(xv3);
                pv[4] = f2bf(xv4); pv[5] = f2bf(xv5); pv[6] = f2bf(xv6); pv[7] = f2bf(xv7);
                *(short8v*)(X0w + ((size_t)w * 64 + lane) * 8) = pv;       // nh = w
            } else if (q == 2) {
                const unsigned lo = (unsigned short)f2bf(xv0);
                *(unsigned*)(X0w + ((size_t)w * 64 + lane) * 8) = (0x3F80u << 16) | lo;
            }
        }
        __syncthreads();   // BARRIER 2: h2(t) / x(t+1) visible
    }

    // -------- epilogue: out[b,0,n,0] (red overlays Al) --------
    #pragma unroll
    for (int mi = 0; mi < 2; ++mi) {
        if (mi < nmt) {
            const int cell = (mt0 + mi) * 4 + q;
            #pragma unroll
            for (int nh = 0; nh < 2; ++nh)
                red[cell * 32 + nh * 16 + cl] = wlin[cell] * macc[mi][nh];
        }
    }
    __syncthreads();
    if (tid < 32) {
        float s = 0.0f;
        for (int j = 0; j < HH; ++j) s += red[j * 32 + tid];
        float ws = 0.0f;
        for (int t2 = 0; t2 < TT; ++t2) ws += wend[t2];
        s += blin[0] * ws + bend[0];
        out[(size_t)(bh * 32 + tid) * NN + n] = s;
    }
}

extern "C" void kernel_launch(void* const* d_in, const int* in_sizes, int n_in,
                              void* d_out, int out_size, void* d_ws, size_t ws_size,
                              hipStream_t stream) {
    const float* x    = (const float*)d_in[0];
    const float* Wih0 = (const float*)d_in[1];
    const float* Whh0 = (const float*)d_in[2];
    const float* bih0 = (const float*)d_in[3];
    const float* bhh0 = (const float*)d_in[4];
    const float* Wih1 = (const float*)d_in[5];
    const float* Whh1 = (const float*)d_in[6];
    const float* bih1 = (const float*)d_in[7];
    const float* bhh1 = (const float*)d_in[8];
    const float* wlin = (const float*)d_in[9];
    const float* blin = (const float*)d_in[10];
    const float* wend = (const float*)d_in[11];
    const float* bend = (const float*)d_in[12];
    (void)d_ws; (void)ws_size; (void)in_sizes; (void)n_in; (void)out_size;

    lstm_one<<<dim3(NN * 2), dim3(1024), LDS_BYTES, stream>>>(
        x, Wih0, Whh0, bih0, bhh0, Wih1, Whh1, bih1, bhh1,
        wlin, blin, wend, bend, (float*)d_out);
}